// Round 2
// baseline (11966.499 us; speedup 1.0000x reference)
//
#include <hip/hip_runtime.h>
#include <stdint.h>

// SimpleRNN on MI355X — persistent kernel, PLAIN launch (R1: cooperative
// launch returned an unchecked error in R0 -> empty stream -> zero output).
// Co-residency by arithmetic: 256 blocks on 256 CUs, 1 block/CU resources
// (__launch_bounds__(256,1): <=512 VGPR; 40KB LDS < 160KB) -> all resident.
//
// B=64, T=512, D=128, H=1024, all fp32.
// Decomposition: 8 batch-groups x 32 column-slices = 256 wgs (1/CU).
//   wg (g,j): rows [8g,8g+8), cols [32j,32j+32), for all t.
//   Wh[:, slice] is REGISTER-resident (float4 w4[32] per thread = 128 VGPRs).
//   h_{t-1} broadcast via d_out (doubles as xp storage, overwritten in place
//   by h_t) with per-producer monotonic flags in d_ws (exact-match check
//   'f==t || f==t+1' -> safe vs 0xAA poison, no init/reset; window
//   |max-min|<=1 holds by data dependence -> no deadlock).

#define Bb 64
#define Tt 512
#define Dd 128
#define Hh 1024
#define NG 8      // batch groups
#define RPG 8     // rows per group
#define NS 32     // col slices per group
#define CPS 32    // cols per slice
#define HROW 1152 // h_lds row stride (floats): 32 chunks * 36
#define KCS 36    // chunk stride (32 data + 4 pad) -> conflict-free reads

__global__ __launch_bounds__(256, 1) void rnn_persist(
    const float* __restrict__ x, const float* __restrict__ Wx,
    const float* __restrict__ Wh, const float* __restrict__ bias,
    float* __restrict__ out, uint32_t* __restrict__ flags)
{
  __shared__ __align__(16) float h_lds[RPG * HROW];   // 36 KB
  __shared__ __align__(16) float red2[4 * RPG * CPS]; // 4 KB

  const int tid = threadIdx.x;
  const int blk = blockIdx.x;
  const int j = blk & (NS - 1);
  const int g = blk >> 5;
  const int rowbase = g * RPG;
  const int colbase = j * CPS;

  // ---------------- Phase 1: xp = x @ Wx + b  (own rows x own cols x all t) --
  {
    const int cx = tid & 31;   // col within slice
    const int rx = tid >> 5;   // row within group
    float wx[Dd];              // Wx column, register-stationary (128 regs)
#pragma unroll
    for (int d = 0; d < Dd; ++d)
      wx[d] = Wx[d * Hh + colbase + cx];
    const float bb = bias[colbase + cx];

    float* x_lds = h_lds;          // reuse as [8][132]
    const int srow = tid >> 5;
    const int sd4 = (tid & 31) * 4;

    for (int tt = 0; tt < Tt; ++tt) {
      float4 xv = *(const float4*)(x + (size_t)(rowbase + srow) * Tt * Dd +
                                   (size_t)tt * Dd + sd4);
      __syncthreads();
      *(float4*)(x_lds + srow * 132 + sd4) = xv;
      __syncthreads();
      float a = 0.f;
#pragma unroll
      for (int d4 = 0; d4 < 32; ++d4) {
        float4 v = *(const float4*)(x_lds + rx * 132 + 4 * d4);
        a += v.x * wx[4 * d4 + 0];
        a += v.y * wx[4 * d4 + 1];
        a += v.z * wx[4 * d4 + 2];
        a += v.w * wx[4 * d4 + 3];
      }
      out[(size_t)(rowbase + rx) * Tt * Hh + (size_t)tt * Hh + colbase + cx] =
          a + bb;
    }
  }

  // ---------------- Load Wh slice into registers ---------------------------
  const int cg = tid & 7;    // col-quad within slice (4 cols)
  const int kc = tid >> 3;   // k-chunk 0..31 (32 k each)
  float4 w4[32];             // Wh[32kc..32kc+32) x 4 cols  (128 regs)
  {
    const float* wp = Wh + (size_t)(32 * kc) * Hh + colbase + 4 * cg;
#pragma unroll
    for (int k = 0; k < 32; ++k)
      w4[k] = *(const float4*)(wp + (size_t)k * Hh);
  }

  const int rr = tid >> 5;
  const int cc = tid & 31;
  const size_t obase0 = (size_t)(rowbase + rr) * Tt * Hh + colbase + cc;
  uint32_t* gflags = flags + g * NS;

  // ---------------- Recurrence -------------------------------------------
  for (int t = 0; t < Tt; ++t) {
    float hres;
    if (t == 0) {
      hres = tanhf(out[obase0]);   // h0 = 0 -> h_1 = tanh(xp_0)
    } else {
      // wait for all 32 slices of h_{t-1} (flag value t; producer may be at t+1)
      if (tid < NS) {
        const uint32_t want = (uint32_t)t;
        while (true) {
          uint32_t f = __hip_atomic_load(&gflags[tid], __ATOMIC_RELAXED,
                                         __HIP_MEMORY_SCOPE_AGENT);
          if ((uint32_t)(f - want) <= 1u) break;
          __builtin_amdgcn_s_sleep(1);
        }
      }
      __syncthreads();
      __threadfence();   // acquire: invalidate stale caches before reading h

      // stage h_{t-1} (8 rows x 1024) into chunk-padded LDS layout
      {
        const int c4 = 4 * tid;        // 0..1020
        const int kcs = c4 >> 5;
        const int kof = c4 & 31;
        const int lof = kcs * KCS + kof;
        const float* hsrc = out + (size_t)rowbase * Tt * Hh +
                            (size_t)(t - 1) * Hh + c4;
        float4 hv[RPG];
#pragma unroll
        for (int q = 0; q < RPG; ++q)
          hv[q] = *(const float4*)(hsrc + (size_t)q * Tt * Hh);
#pragma unroll
        for (int q = 0; q < RPG; ++q)
          *(float4*)(h_lds + q * HROW + lof) = hv[q];
      }
      const float xp_val = out[obase0 + (size_t)t * Hh]; // hidden under GEMM
      __syncthreads();

      // GEMM partials: this thread's 32-k window x 4 cols x 8 rows
      float4 acc[RPG];
#pragma unroll
      for (int r = 0; r < RPG; ++r) acc[r] = make_float4(0.f, 0.f, 0.f, 0.f);
#pragma unroll
      for (int r = 0; r < RPG; ++r) {
        const float* hrow = h_lds + r * HROW + kc * KCS;
#pragma unroll
        for (int k4 = 0; k4 < 8; ++k4) {
          float4 hv = *(const float4*)(hrow + 4 * k4);
          float4 w0 = w4[4 * k4 + 0], w1 = w4[4 * k4 + 1];
          float4 w2 = w4[4 * k4 + 2], w3 = w4[4 * k4 + 3];
          acc[r].x += hv.x * w0.x; acc[r].y += hv.x * w0.y;
          acc[r].z += hv.x * w0.z; acc[r].w += hv.x * w0.w;
          acc[r].x += hv.y * w1.x; acc[r].y += hv.y * w1.y;
          acc[r].z += hv.y * w1.z; acc[r].w += hv.y * w1.w;
          acc[r].x += hv.z * w2.x; acc[r].y += hv.z * w2.y;
          acc[r].z += hv.z * w2.z; acc[r].w += hv.z * w2.w;
          acc[r].x += hv.w * w3.x; acc[r].y += hv.w * w3.y;
          acc[r].z += hv.w * w3.z; acc[r].w += hv.w * w3.w;
        }
      }

      // reduce over k-chunks: in-wave butterfly (kc bits are lane bits 3..5)
#pragma unroll
      for (int m = 8; m <= 32; m <<= 1) {
#pragma unroll
        for (int r = 0; r < RPG; ++r) {
          acc[r].x += __shfl_xor(acc[r].x, m, 64);
          acc[r].y += __shfl_xor(acc[r].y, m, 64);
          acc[r].z += __shfl_xor(acc[r].z, m, 64);
          acc[r].w += __shfl_xor(acc[r].w, m, 64);
        }
      }
      if ((tid & 63) < 8) {          // one lane per col-quad per wave
        const int w = tid >> 6;
#pragma unroll
        for (int r = 0; r < RPG; ++r)
          *(float4*)(&red2[(w * RPG + r) * CPS + 4 * cg]) = acc[r];
      }
      __syncthreads();
      float s = red2[(0 * RPG + rr) * CPS + cc] +
                red2[(1 * RPG + rr) * CPS + cc] +
                red2[(2 * RPG + rr) * CPS + cc] +
                red2[(3 * RPG + rr) * CPS + cc];
      hres = tanhf(s + xp_val);
    }

    out[obase0 + (size_t)t * Hh] = hres;  // overwrite xp slot with h_t
    __syncthreads();                       // vmcnt drained at barrier
    if (tid == 0)
      __hip_atomic_store(&gflags[j], (uint32_t)(t + 1), __ATOMIC_RELEASE,
                         __HIP_MEMORY_SCOPE_AGENT);
  }
}

extern "C" void kernel_launch(void* const* d_in, const int* in_sizes, int n_in,
                              void* d_out, int out_size, void* d_ws,
                              size_t ws_size, hipStream_t stream) {
  const float* x  = (const float*)d_in[0];
  const float* Wx = (const float*)d_in[1];
  const float* Wh = (const float*)d_in[2];
  const float* bv = (const float*)d_in[3];
  float* out = (float*)d_out;
  uint32_t* flags = (uint32_t*)d_ws;  // 8*32 u32 = 1 KB; 0xAA poison is safe

  rnn_persist<<<dim3(NG * NS), dim3(256), 0, stream>>>(x, Wx, Wh, bv, out,
                                                       flags);
}

// Round 4
// 4917.901 us; speedup vs baseline: 2.4333x; 2.4333x over previous
//
#include <hip/hip_runtime.h>
#include <stdint.h>

// SimpleRNN on MI355X — persistent kernel, plain launch (R3).
//
// R1 (release+threadfence, cached data): PASS, 23.4 us/step — fences flush a
//   DIRTY L2 every step + post-inv refetch storm (FETCH 607 MB).
// R2 (all-relaxed, sc1-bypass data): FAIL absmax 0.34 — visibility race:
//   vmcnt-ack of an sc1 store is not proof of LLC visibility, and relaxed-
//   everything licenses compiler reordering of the staging loads.
// R3 = R2's bypassing data path + REAL release/acquire edges whose cache-
//   maintenance ops are cheap because L2 never holds dirty out[] lines:
//   - producer (tid 0): RELEASE agent flag store (wbl2 walks a clean L2)
//   - consumer (wave 0): acquire agent fence after poll (inv of clean L2;
//     nothing in the loop re-reads through L2 afterward)
//
// B=64, T=512, D=128, H=1024, fp32. 8 batch-groups x 32 col-slices = 256 wgs
// (1/CU). Wh[:,slice] register-resident (float4 w4[32] = 128 VGPRs/thread).
// Flags: monotonic exact-match 'f-t<=1' -> 0xAA-poison safe, no init/reset.

#define Bb 64
#define Tt 512
#define Dd 128
#define Hh 1024
#define NG 8      // batch groups
#define RPG 8     // rows per group
#define NS 32     // col slices per group
#define CPS 32    // cols per slice
#define HROW 1152 // h_lds row stride (floats): 32 chunks * 36
#define KCS 36    // chunk stride (32 data + 4 pad) -> conflict-free reads

typedef unsigned long long u64;

__device__ __forceinline__ float agent_load_f32(const float* p) {
  return __hip_atomic_load(p, __ATOMIC_RELAXED, __HIP_MEMORY_SCOPE_AGENT);
}
__device__ __forceinline__ void agent_store_f32(float* p, float v) {
  __hip_atomic_store(p, v, __ATOMIC_RELAXED, __HIP_MEMORY_SCOPE_AGENT);
}
__device__ __forceinline__ float2 agent_load_f32x2(const float* p) {
  union { u64 u; float2 f; } c;
  c.u = __hip_atomic_load((const u64*)p, __ATOMIC_RELAXED,
                          __HIP_MEMORY_SCOPE_AGENT);
  return c.f;
}

__global__ __launch_bounds__(256, 1) void rnn_persist(
    const float* __restrict__ x, const float* __restrict__ Wx,
    const float* __restrict__ Wh, const float* __restrict__ bias,
    float* __restrict__ out, uint32_t* __restrict__ flags)
{
  __shared__ __align__(16) float h_lds[RPG * HROW];   // 36 KB
  __shared__ __align__(16) float red2[4 * RPG * CPS]; // 4 KB

  const int tid = threadIdx.x;
  const int blk = blockIdx.x;
  const int j = blk & (NS - 1);
  const int g = blk >> 5;
  const int rowbase = g * RPG;
  const int colbase = j * CPS;

  // ---------------- Phase 1: xp = x @ Wx + b -------------------------------
  {
    const int cx = tid & 31;   // col within slice
    const int rx = tid >> 5;   // row within group
    float wx[Dd];              // Wx column, register-stationary
#pragma unroll
    for (int d = 0; d < Dd; ++d)
      wx[d] = Wx[d * Hh + colbase + cx];
    const float bb = bias[colbase + cx];

    float* x_lds = h_lds;          // reuse as [8][132]
    const int srow = tid >> 5;
    const int sd4 = (tid & 31) * 4;

    for (int tt = 0; tt < Tt; ++tt) {
      float4 xv = *(const float4*)(x + (size_t)(rowbase + srow) * Tt * Dd +
                                   (size_t)tt * Dd + sd4);
      __syncthreads();
      *(float4*)(x_lds + srow * 132 + sd4) = xv;
      __syncthreads();
      float a = 0.f;
#pragma unroll
      for (int d4 = 0; d4 < 32; ++d4) {
        float4 v = *(const float4*)(x_lds + rx * 132 + 4 * d4);
        a += v.x * wx[4 * d4 + 0];
        a += v.y * wx[4 * d4 + 1];
        a += v.z * wx[4 * d4 + 2];
        a += v.w * wx[4 * d4 + 3];
      }
      // sc1 store: out[] lines must NEVER be dirty in L2 (single-copy rule)
      agent_store_f32(out + (size_t)(rowbase + rx) * Tt * Hh +
                          (size_t)tt * Hh + colbase + cx,
                      a + bb);
    }
  }

  // ---------------- Load Wh slice into registers ---------------------------
  const int cg = tid & 7;    // col-quad within slice (4 cols)
  const int kc = tid >> 3;   // k-chunk 0..31 (32 k each)
  float4 w4[32];             // Wh[32kc..32kc+32) x 4 cols  (128 regs)
  {
    const float* wp = Wh + (size_t)(32 * kc) * Hh + colbase + 4 * cg;
#pragma unroll
    for (int k = 0; k < 32; ++k)
      w4[k] = *(const float4*)(wp + (size_t)k * Hh);
  }

  const int rr = tid >> 5;
  const int cc = tid & 31;
  const size_t obase0 = (size_t)(rowbase + rr) * Tt * Hh + colbase + cc;
  uint32_t* gflags = flags + g * NS;

  // ---------------- Recurrence -------------------------------------------
  for (int t = 0; t < Tt; ++t) {
    float hres;
    if (t == 0) {
      hres = tanhf(agent_load_f32(out + obase0));  // h0=0 -> h_1 = tanh(xp_0)
    } else {
      // wait for all 32 slices of h_{t-1} (flag t; producer may be at t+1)
      if (tid < 64) {
        if (tid < NS) {
          const uint32_t want = (uint32_t)t;
          while (true) {
            uint32_t f = __hip_atomic_load(&gflags[tid], __ATOMIC_RELAXED,
                                           __HIP_MEMORY_SCOPE_AGENT);
            if ((uint32_t)(f - want) <= 1u) break;
            __builtin_amdgcn_s_sleep(1);
          }
        }
        // acquire edge, wave 0 only: pairs with producers' release stores.
        // L2 is clean of out[] lines -> inv walk is cheap, no refetch after.
        __builtin_amdgcn_fence(__ATOMIC_ACQUIRE, "agent");
      }
      __syncthreads();   // other waves' loads cannot cross this barrier

      // stage h_{t-1} (8 rows x 1024) into chunk-padded LDS layout
      {
        const int c4 = 4 * tid;        // 0..1020
        const int kcs = c4 >> 5;
        const int kof = c4 & 31;
        const int lof = kcs * KCS + kof;
        const float* hsrc = out + (size_t)rowbase * Tt * Hh +
                            (size_t)(t - 1) * Hh + c4;
        float2 lo[RPG], hi[RPG];
#pragma unroll
        for (int q = 0; q < RPG; ++q) {
          const float* p = hsrc + (size_t)q * Tt * Hh;
          lo[q] = agent_load_f32x2(p);
          hi[q] = agent_load_f32x2(p + 2);
        }
#pragma unroll
        for (int q = 0; q < RPG; ++q)
          *(float4*)(h_lds + q * HROW + lof) =
              make_float4(lo[q].x, lo[q].y, hi[q].x, hi[q].y);
      }
      const float xp_val = agent_load_f32(out + obase0 + (size_t)t * Hh);
      __syncthreads();

      // GEMM partials: this thread's 32-k window x 4 cols x 8 rows
      float4 acc[RPG];
#pragma unroll
      for (int r = 0; r < RPG; ++r) acc[r] = make_float4(0.f, 0.f, 0.f, 0.f);
#pragma unroll
      for (int r = 0; r < RPG; ++r) {
        const float* hrow = h_lds + r * HROW + kc * KCS;
#pragma unroll
        for (int k4 = 0; k4 < 8; ++k4) {
          float4 hv = *(const float4*)(hrow + 4 * k4);
          float4 w0 = w4[4 * k4 + 0], w1 = w4[4 * k4 + 1];
          float4 w2 = w4[4 * k4 + 2], w3 = w4[4 * k4 + 3];
          acc[r].x += hv.x * w0.x; acc[r].y += hv.x * w0.y;
          acc[r].z += hv.x * w0.z; acc[r].w += hv.x * w0.w;
          acc[r].x += hv.y * w1.x; acc[r].y += hv.y * w1.y;
          acc[r].z += hv.y * w1.z; acc[r].w += hv.y * w1.w;
          acc[r].x += hv.z * w2.x; acc[r].y += hv.z * w2.y;
          acc[r].z += hv.z * w2.z; acc[r].w += hv.z * w2.w;
          acc[r].x += hv.w * w3.x; acc[r].y += hv.w * w3.y;
          acc[r].z += hv.w * w3.z; acc[r].w += hv.w * w3.w;
        }
      }

      // reduce over k-chunks: in-wave butterfly (kc bits are lane bits 3..5)
#pragma unroll
      for (int m = 8; m <= 32; m <<= 1) {
#pragma unroll
        for (int r = 0; r < RPG; ++r) {
          acc[r].x += __shfl_xor(acc[r].x, m, 64);
          acc[r].y += __shfl_xor(acc[r].y, m, 64);
          acc[r].z += __shfl_xor(acc[r].z, m, 64);
          acc[r].w += __shfl_xor(acc[r].w, m, 64);
        }
      }
      if ((tid & 63) < 8) {          // one lane per col-quad per wave
        const int w = tid >> 6;
#pragma unroll
        for (int r = 0; r < RPG; ++r)
          *(float4*)(&red2[(w * RPG + r) * CPS + 4 * cg]) = acc[r];
      }
      __syncthreads();
      float s = red2[(0 * RPG + rr) * CPS + cc] +
                red2[(1 * RPG + rr) * CPS + cc] +
                red2[(2 * RPG + rr) * CPS + cc] +
                red2[(3 * RPG + rr) * CPS + cc];
      hres = tanhf(s + xp_val);
    }

    agent_store_f32(out + obase0 + (size_t)t * Hh, hres);  // xp slot -> h_t
    __syncthreads();   // all waves' h stores drained (vmcnt(0)) before flag
    if (tid == 0)
      __hip_atomic_store(&gflags[j], (uint32_t)(t + 1), __ATOMIC_RELEASE,
                         __HIP_MEMORY_SCOPE_AGENT);  // wbl2 walks a CLEAN L2
  }
}

extern "C" void kernel_launch(void* const* d_in, const int* in_sizes, int n_in,
                              void* d_out, int out_size, void* d_ws,
                              size_t ws_size, hipStream_t stream) {
  const float* x  = (const float*)d_in[0];
  const float* Wx = (const float*)d_in[1];
  const float* Wh = (const float*)d_in[2];
  const float* bv = (const float*)d_in[3];
  float* out = (float*)d_out;
  uint32_t* flags = (uint32_t*)d_ws;  // 8*32 u32 = 1 KB; 0xAA poison is safe

  rnn_persist<<<dim3(NG * NS), dim3(256), 0, stream>>>(x, Wx, Wh, bv, out,
                                                       flags);
}